// Round 13
// baseline (188.064 us; speedup 1.0000x reference)
//
#include <hip/hip_runtime.h>

// FullNN: per-atom MLP (FEAT=64 -> tanh(HID=64) -> 1) + segment-sum over 32768 structs.
// Round 13: backwards arithmetic on rounds 8-12 (BW 3.75 TB/s at 250-600ns latency
// => only ~4-13KB outstanding per CU) proves the software pipelines never ran: the
// inline-asm "memory" clobbers (rounds 10-12) forced vmcnt drains every iteration,
// and the reg-copy rotation (rounds 4-8) waited with only 4KB queued. This round:
// PURE C depth-3 pipeline -- no asm, no LDS, no barriers; the compiler emits counted
// vmcnt (proven, m97 asm) when nothing interferes. Stage = convert slot S (wait
// leaves 2 slots in flight) -> refill S from t+3nw -> compute. W1 frags in registers;
// wave-uniform SGPR addressing (saddr-form loads, per-lane xoff in one VGPR).
//
// MFMA mfma_f32_16x16x32_bf16, swapped H^T = W1^T @ x^T (learn_hip m89/m97):
//   A: row=lane&15, k=(lane>>4)*8+i -> W1^T frag (registers)
//   B: col=lane&15 (= atom), k=(lane>>4)*8+i -> x^T frag
//   D: col=lane&15 (= atom), j=16t+kg*4+r    -> in-lane W2 reduce, 2 shfls

typedef __attribute__((ext_vector_type(8))) short bf16x8;
typedef __attribute__((ext_vector_type(4))) float f32x4;

struct ElemPtrs {
    const float* x;
    const int*   idx;
    const float* W1;
    const float* b1;
    const float* W2;
    const float* b2;
};
struct Params {
    ElemPtrs e[3];
    int n_tiles;   // atoms / 16
};

__device__ __forceinline__ short f2bf(float f) {
    __bf16 h = (__bf16)f;           // hardware RNE; pairs into v_cvt_pk_bf16_f32
    return __builtin_bit_cast(short, h);
}

__device__ __forceinline__ float fast_tanh(float v) {
    v = __builtin_amdgcn_fmed3f(v, -10.0f, 10.0f);
    float t = __builtin_amdgcn_exp2f(v * 2.8853900817779268f); // 2^(2v*log2 e)
    return (t - 1.0f) * __builtin_amdgcn_rcpf(t + 1.0f);
}

__global__ __launch_bounds__(256) void atom_mlp(Params p, float* __restrict__ out)
{
    const ElemPtrs ep = p.e[blockIdx.y];   // uniform index -> scalar code

    const int tid  = threadIdx.x;
    const int lane = tid & 63;
    const int col  = lane & 15;    // atom within tile
    const int kg   = lane >> 4;    // k-group

    // ---- persistent W1^T A-fragments (32 VGPR) ----
    bf16x8 Wf[2][4];
    #pragma unroll
    for (int s = 0; s < 2; ++s)
        #pragma unroll
        for (int t = 0; t < 4; ++t)
            #pragma unroll
            for (int i = 0; i < 8; ++i)
                Wf[s][t][i] = f2bf(ep.W1[(s * 32 + kg * 8 + i) * 64 + 16 * t + col]);

    // per-lane b1 (MFMA C-init) and W2, j = 16t + kg*4 + r
    f32x4 b1c[4], w2c[4];
    #pragma unroll
    for (int t = 0; t < 4; ++t)
        #pragma unroll
        for (int r = 0; r < 4; ++r) {
            b1c[t][r] = ep.b1[16 * t + kg * 4 + r];
            w2c[t][r] = ep.W2[16 * t + kg * 4 + r];
        }
    const float b2v = ep.b2[0];

    const int nt  = p.n_tiles;
    const int wid = (blockIdx.x * 256 + tid) >> 6;
    const int nw  = (gridDim.x * 256) >> 6;

    // byte addressing: tile T at byte T*4096 (uniform, SGPR math); lane offset xoff
    const char* __restrict__ xb = (const char*)ep.x;
    const char* __restrict__ ib = (const char*)ep.idx;
    const unsigned xoff = (unsigned)(col * 256 + kg * 32);   // bytes into tile
    const unsigned ioff = (unsigned)(col * 4);               // bytes into tile idx

    int tA = wid;
    if (tA >= nt) return;                  // wave-uniform

    // 5 loads per slot: 4 x f32x4 (x) + 1 int (idx)
#define SLOT_LOAD(S, T)                                                           \
    {                                                                             \
        const unsigned xo = (unsigned)(T) * 4096u + xoff;                         \
        const unsigned io = (unsigned)(T) * 64u  + ioff;                          \
        c##S##0 = *reinterpret_cast<const f32x4*>(xb + xo);                       \
        c##S##1 = *reinterpret_cast<const f32x4*>(xb + xo + 16);                  \
        c##S##2 = *reinterpret_cast<const f32x4*>(xb + xo + 128);                 \
        c##S##3 = *reinterpret_cast<const f32x4*>(xb + xo + 144);                 \
        ia##S   = *reinterpret_cast<const int*>(ib + io);                         \
    }

    // convert current slot, refill it 3 tiles ahead, compute, atomic
#define SLOT_STAGE(S)                                                             \
    {                                                                             \
        bf16x8 X0, X1;                                                            \
        X0[0]=f2bf(c##S##0[0]); X0[1]=f2bf(c##S##0[1]);                           \
        X0[2]=f2bf(c##S##0[2]); X0[3]=f2bf(c##S##0[3]);                           \
        X0[4]=f2bf(c##S##1[0]); X0[5]=f2bf(c##S##1[1]);                           \
        X0[6]=f2bf(c##S##1[2]); X0[7]=f2bf(c##S##1[3]);                           \
        X1[0]=f2bf(c##S##2[0]); X1[1]=f2bf(c##S##2[1]);                           \
        X1[2]=f2bf(c##S##2[2]); X1[3]=f2bf(c##S##2[3]);                           \
        X1[4]=f2bf(c##S##3[0]); X1[5]=f2bf(c##S##3[1]);                           \
        X1[6]=f2bf(c##S##3[2]); X1[7]=f2bf(c##S##3[3]);                           \
        const int iaCur = ia##S;                                                  \
        const bool hN = (tN < nt);            /* wave-uniform */                  \
        if (hN) SLOT_LOAD(S, tN);                                                 \
        live##S = hN;                                                             \
        tN += nw;                                                                 \
        f32x4 a0 = __builtin_amdgcn_mfma_f32_16x16x32_bf16(Wf[0][0], X0, b1c[0], 0, 0, 0); \
        f32x4 a1 = __builtin_amdgcn_mfma_f32_16x16x32_bf16(Wf[0][1], X0, b1c[1], 0, 0, 0); \
        f32x4 a2 = __builtin_amdgcn_mfma_f32_16x16x32_bf16(Wf[0][2], X0, b1c[2], 0, 0, 0); \
        f32x4 a3 = __builtin_amdgcn_mfma_f32_16x16x32_bf16(Wf[0][3], X0, b1c[3], 0, 0, 0); \
        a0 = __builtin_amdgcn_mfma_f32_16x16x32_bf16(Wf[1][0], X1, a0, 0, 0, 0);  \
        a1 = __builtin_amdgcn_mfma_f32_16x16x32_bf16(Wf[1][1], X1, a1, 0, 0, 0);  \
        a2 = __builtin_amdgcn_mfma_f32_16x16x32_bf16(Wf[1][2], X1, a2, 0, 0, 0);  \
        a3 = __builtin_amdgcn_mfma_f32_16x16x32_bf16(Wf[1][3], X1, a3, 0, 0, 0);  \
        float ev;                                                                 \
        ev  = fast_tanh(a0[0]) * w2c[0][0];                                       \
        ev += fast_tanh(a0[1]) * w2c[0][1];                                       \
        ev += fast_tanh(a0[2]) * w2c[0][2];                                       \
        ev += fast_tanh(a0[3]) * w2c[0][3];                                       \
        ev += fast_tanh(a1[0]) * w2c[1][0];                                       \
        ev += fast_tanh(a1[1]) * w2c[1][1];                                       \
        ev += fast_tanh(a1[2]) * w2c[1][2];                                       \
        ev += fast_tanh(a1[3]) * w2c[1][3];                                       \
        ev += fast_tanh(a2[0]) * w2c[2][0];                                       \
        ev += fast_tanh(a2[1]) * w2c[2][1];                                       \
        ev += fast_tanh(a2[2]) * w2c[2][2];                                       \
        ev += fast_tanh(a2[3]) * w2c[2][3];                                       \
        ev += fast_tanh(a3[0]) * w2c[3][0];                                       \
        ev += fast_tanh(a3[1]) * w2c[3][1];                                       \
        ev += fast_tanh(a3[2]) * w2c[3][2];                                       \
        ev += fast_tanh(a3[3]) * w2c[3][3];                                       \
        ev += __shfl_xor(ev, 16);                                                 \
        ev += __shfl_xor(ev, 32);                                                 \
        if (lane < 16) atomicAdd(&out[iaCur], ev + b2v);                          \
    }

    f32x4 cA0, cA1, cA2, cA3, cB0, cB1, cB2, cB3, cC0, cC1, cC2, cC3;
    int iaA, iaB, iaC;
    bool liveA = true, liveB, liveC;

    // prologue: fill 3 slots
    SLOT_LOAD(A, tA);
    const int tB0 = tA + nw;
    liveB = (tB0 < nt);
    if (liveB) SLOT_LOAD(B, tB0);
    const int tC0 = tA + 2 * nw;
    liveC = (tC0 < nt);
    if (liveC) SLOT_LOAD(C, tC0);

    int tN = tA + 3 * nw;   // next tile index to stage (into the slot just consumed)

    while (true) {
        SLOT_STAGE(A);
        if (!liveB) break;
        SLOT_STAGE(B);
        if (!liveC) break;
        SLOT_STAGE(C);
        if (!liveA) break;
    }

#undef SLOT_LOAD
#undef SLOT_STAGE
}

extern "C" void kernel_launch(void* const* d_in, const int* in_sizes, int n_in,
                              void* d_out, int out_size, void* d_ws, size_t ws_size,
                              hipStream_t stream) {
    Params p;
    for (int e = 0; e < 3; ++e) {
        p.e[e].x   = (const float*)d_in[6 * e + 0];
        p.e[e].idx = (const int*)  d_in[6 * e + 1];
        p.e[e].W1  = (const float*)d_in[6 * e + 2];
        p.e[e].b1  = (const float*)d_in[6 * e + 3];
        p.e[e].W2  = (const float*)d_in[6 * e + 4];
        p.e[e].b2  = (const float*)d_in[6 * e + 5];
    }
    const int n_atoms = in_sizes[0] / 64;
    p.n_tiles = n_atoms / 16;   // 62,500

    float* out = (float*)d_out;
    // d_out is poisoned (0xAA) before timing and NOT re-zeroed between replays.
    hipMemsetAsync(out, 0, (size_t)out_size * sizeof(float), stream);

    dim3 grid(683, 3);   // 2049 blocks; grid-stride; residency set by VGPR
    atom_mlp<<<grid, 256, 0, stream>>>(p, out);
}